// Round 9
// baseline (444.564 us; speedup 1.0000x reference)
//
#include <hip/hip_runtime.h>

// ---------------------------------------------------------------------------
// Drug-path-only GNN (gene path is dead code w.r.t. outputs).
// Round 9: non-temporal streaming. Round-8 profile: fill8 WRITE_SIZE 53.6MB
// for a 3MB csr buffer (each line evicted ~18x, ~2 stores/residency) -- the
// streaming edge-list reads LRU-evict the partially-filled scatter lines.
// Fix: nt (evict-first) loads for all streamed data (edge indices, csr
// replay, selfb) + nt stores for score outputs; scatter stores/atomics stay
// cached so lines accumulate. Grids 2048 for latency hiding.
// ---------------------------------------------------------------------------

#define NPART 8

__device__ inline float bf2f(unsigned short b) {
    union { float f; unsigned u; } c; c.u = (unsigned)b << 16; return c.f;
}
__device__ inline unsigned short f2bf(float x) {
    union { float f; unsigned u; } c; c.f = x;
    unsigned r = c.u + 0x7FFF + ((c.u >> 16) & 1);
    return (unsigned short)(r >> 16);
}

// out[m][n] = bf16(sum_k A[m][k]*W[k][n]); KOUT==64; weights in VGPRs
template<int KIN>
__global__ __launch_bounds__(256) void gemm_reg_kernel(const float* __restrict__ A,
                                                       const float* __restrict__ W,
                                                       unsigned short* __restrict__ out,
                                                       int M) {
    const int lane = threadIdx.x & 63;
    const int gwave = blockIdx.x * (blockDim.x >> 6) + (threadIdx.x >> 6);
    const int nwave = gridDim.x * (blockDim.x >> 6);
    float w[KIN];
#pragma unroll
    for (int k = 0; k < KIN; ++k) w[k] = W[k * 64 + lane];
    for (int m0 = gwave * 2; m0 < M; m0 += nwave * 2) {
        const int mu = __builtin_amdgcn_readfirstlane(m0);
        const float* a0 = A + (size_t)mu * KIN;
        const float* a1 = a0 + KIN;
        const bool two = (mu + 1) < M;
        float acc0 = 0.0f, acc1 = 0.0f;
#pragma unroll
        for (int k = 0; k < KIN; ++k) {
            const float av0 = a0[k];
            const float av1 = two ? a1[k] : 0.0f;
            acc0 = fmaf(av0, w[k], acc0);
            acc1 = fmaf(av1, w[k], acc1);
        }
        out[(size_t)mu * 64 + lane] = f2bf(acc0);
        if (two) out[(size_t)(mu + 1) * 64 + lane] = f2bf(acc1);
    }
}

// layer-2 pair: KIN=64, KOUT=32. Lanes 0..31 -> Wa cols, lanes 32..63 -> Wb.
__global__ __launch_bounds__(256) void gemm2_reg_kernel(const float* __restrict__ A,
                                                        const float* __restrict__ Wa,
                                                        const float* __restrict__ Wb,
                                                        unsigned short* __restrict__ out_a,
                                                        unsigned short* __restrict__ out_b,
                                                        int M) {
    const int lane = threadIdx.x & 63;
    const int col = lane & 31;
    const float* Wm = (lane < 32) ? Wa : Wb;
    unsigned short* om = (lane < 32) ? out_a : out_b;
    const int gwave = blockIdx.x * (blockDim.x >> 6) + (threadIdx.x >> 6);
    const int nwave = gridDim.x * (blockDim.x >> 6);
    float w[64];
#pragma unroll
    for (int k = 0; k < 64; ++k) w[k] = Wm[k * 32 + col];
    for (int m0 = gwave * 2; m0 < M; m0 += nwave * 2) {
        const int mu = __builtin_amdgcn_readfirstlane(m0);
        const float* a0 = A + (size_t)mu * 64;
        const float* a1 = a0 + 64;
        const bool two = (mu + 1) < M;
        float acc0 = 0.0f, acc1 = 0.0f;
#pragma unroll
        for (int k = 0; k < 64; ++k) {
            const float av0 = a0[k];
            const float av1 = two ? a1[k] : 0.0f;
            acc0 = fmaf(av0, w[k], acc0);
            acc1 = fmaf(av1, w[k], acc1);
        }
        om[(size_t)mu * 32 + col] = f2bf(acc0);
        if (two) om[(size_t)(mu + 1) * 32 + col] = f2bf(acc1);
    }
}

// per-edge-chunk degree histogram into partition-private deg8[p][n]
__global__ __launch_bounds__(256) void degree8_kernel(const int* __restrict__ dst,
                                                      int* __restrict__ deg8,
                                                      int E, int chunk, int N) {
    const int p = blockIdx.x & (NPART - 1);
    const int lo = p * chunk;
    const int hi = min(lo + chunk, E);
    int* __restrict__ deg = deg8 + (size_t)p * N;
    const int bip = blockIdx.x >> 3;
    const int stride = (gridDim.x >> 3) * 256;
    for (int e = lo + bip * 256 + threadIdx.x; e < hi; e += stride) {
        const int d = __builtin_nontemporal_load(dst + e);
        atomicAdd(&deg[d], 1);
    }
}

// 8 independent within-partition scans; block p's base offset = p*chunk.
__global__ __launch_bounds__(1024) void scan8_kernel(const int* __restrict__ deg8,
                                                     int* __restrict__ off8,
                                                     int* __restrict__ cursor8,
                                                     int N, int chunk) {
    const int p = blockIdx.x;
    const int base = p * chunk;
    const int* __restrict__ deg = deg8 + (size_t)p * N;
    int* __restrict__ off = off8 + (size_t)p * N;
    int* __restrict__ cur = cursor8 + (size_t)p * N;
    __shared__ int part[1024];
    const int t = threadIdx.x;
    const int per = (N + 1023) / 1024;
    const int beg = t * per;
    const int end = min(beg + per, N);
    int s = 0;
    for (int i = beg; i < end; ++i) s += deg[i];
    part[t] = s;
    __syncthreads();
    for (int d = 1; d < 1024; d <<= 1) {
        int v = (t >= d) ? part[t - d] : 0;
        __syncthreads();
        part[t] += v;
        __syncthreads();
    }
    int run = base + ((t == 0) ? 0 : part[t - 1]);
    for (int i = beg; i < end; ++i) { off[i] = run; cur[i] = run; run += deg[i]; }
}

// edge-chunk-partitioned bucket fill; nt edge reads, cached scatter stores.
__global__ __launch_bounds__(256) void fill8_kernel(const int* __restrict__ src,
                                                    const int* __restrict__ dst,
                                                    int* __restrict__ cursor8,
                                                    unsigned short* __restrict__ csr_src,
                                                    int E, int chunk, int N) {
    const int p = blockIdx.x & (NPART - 1);
    const int lo = p * chunk;
    const int hi = min(lo + chunk, E);
    int* __restrict__ cursor = cursor8 + (size_t)p * N;
    const int bip = blockIdx.x >> 3;
    const int stride = (gridDim.x >> 3) * 256;
    for (int e = lo + bip * 256 + threadIdx.x; e < hi; e += stride) {
        const int d = __builtin_nontemporal_load(dst + e);
        const int s = __builtin_nontemporal_load(src + e);
        const int pos = atomicAdd(&cursor[d], 1);
        csr_src[pos] = (unsigned short)s;
    }
}

// One W-lane group per dst node: loop 8 partition sub-segments over bf16 msg,
// fp32 accumulate, fused mean+self+bias(+relu). OBF: write bf16 output.
template<int W, bool RELU, bool OBF>
__global__ __launch_bounds__(256) void gather_combine_kernel(
        const unsigned short* __restrict__ msg,
        const unsigned short* __restrict__ csr_src,
        const int* __restrict__ off8, const int* __restrict__ end8,
        const unsigned short* __restrict__ selfb, const float* __restrict__ b,
        void* __restrict__ out_, int N) {
    const int GRP = 256 / W;
    const int g = threadIdx.x / W;
    const int lane = threadIdx.x % W;
    const float bk = b[lane];
    for (int n = blockIdx.x * GRP + g; n < N; n += gridDim.x * GRP) {
        float acc = 0.0f;
        int cnt = 0;
        for (int p = 0; p < NPART; ++p) {
            const int beg = off8[(size_t)p * N + n];
            const int end = end8[(size_t)p * N + n];
            cnt += end - beg;
            int i = beg;
            for (; i + 4 <= end; i += 4) {
                const int s0 = __builtin_nontemporal_load(csr_src + i);
                const int s1 = __builtin_nontemporal_load(csr_src + i + 1);
                const int s2 = __builtin_nontemporal_load(csr_src + i + 2);
                const int s3 = __builtin_nontemporal_load(csr_src + i + 3);
                const float v0 = bf2f(msg[(size_t)s0 * W + lane]);
                const float v1 = bf2f(msg[(size_t)s1 * W + lane]);
                const float v2 = bf2f(msg[(size_t)s2 * W + lane]);
                const float v3 = bf2f(msg[(size_t)s3 * W + lane]);
                acc += (v0 + v1) + (v2 + v3);
            }
            for (; i < end; ++i)
                acc += bf2f(msg[(size_t)__builtin_nontemporal_load(csr_src + i) * W + lane]);
        }
        const float d = (cnt > 0) ? (float)cnt : 1.0f;
        float v = acc / d + bf2f(__builtin_nontemporal_load(selfb + (size_t)n * W + lane)) + bk;
        if (RELU) v = fmaxf(v, 0.0f);
        if (OBF) ((unsigned short*)out_)[(size_t)n * W + lane] = f2bf(v);
        else     ((float*)out_)[(size_t)n * W + lane] = v;
    }
}

// fused pos+neg scorer over bf16 h: 8 lanes/edge, nt index reads + nt output
__global__ __launch_bounds__(256) void score2_kernel(const unsigned short* __restrict__ h,
                                                     const int* __restrict__ sA,
                                                     const int* __restrict__ dA,
                                                     const int* __restrict__ sB,
                                                     const int* __restrict__ dB,
                                                     const float* __restrict__ wrel,
                                                     float* __restrict__ outA,
                                                     float* __restrict__ outB,
                                                     int EA, int EB) {
    const int lj = threadIdx.x & 7;
    const size_t grp = ((size_t)blockIdx.x * blockDim.x + threadIdx.x) >> 3;
    const size_t ngrp = ((size_t)gridDim.x * blockDim.x) >> 3;
    const float4 w = *(const float4*)(wrel + lj * 4);
    const size_t total = (size_t)EA + (size_t)EB;
    for (size_t e = grp; e < total; e += ngrp) {
        int s, d; float* o;
        if (e < (size_t)EA) {
            s = __builtin_nontemporal_load(sA + e);
            d = __builtin_nontemporal_load(dA + e);
            o = outA + e;
        } else {
            const size_t e2 = e - EA;
            s = __builtin_nontemporal_load(sB + e2);
            d = __builtin_nontemporal_load(dB + e2);
            o = outB + e2;
        }
        const ushort4 hs = *(const ushort4*)(h + (size_t)s * 32 + lj * 4);
        const ushort4 hd = *(const ushort4*)(h + (size_t)d * 32 + lj * 4);
        float p = bf2f(hs.x) * w.x * bf2f(hd.x) + bf2f(hs.y) * w.y * bf2f(hd.y) +
                  bf2f(hs.z) * w.z * bf2f(hd.z) + bf2f(hs.w) * w.w * bf2f(hd.w);
        p += __shfl_xor(p, 1, 64);
        p += __shfl_xor(p, 2, 64);
        p += __shfl_xor(p, 4, 64);
        if (lj == 0) __builtin_nontemporal_store(p, o);
    }
}

extern "C" void kernel_launch(void* const* d_in, const int* in_sizes, int n_in,
                              void* d_out, int out_size, void* d_ws, size_t ws_size,
                              hipStream_t stream) {
    const float* feat_drug    = (const float*)d_in[0];
    const int*   dd_src       = (const int*)d_in[2];
    const int*   dd_dst       = (const int*)d_in[3];
    const int*   neg_src      = (const int*)d_in[8];
    const int*   neg_dst      = (const int*)d_in[9];
    const float* W1_dd        = (const float*)d_in[10];
    const float* W1_self_drug = (const float*)d_in[13];
    const float* b1           = (const float*)d_in[15];
    const float* W2_dd        = (const float*)d_in[16];
    const float* W2_self_drug = (const float*)d_in[19];
    const float* b2           = (const float*)d_in[21];
    const float* w_rel        = (const float*)d_in[22];

    const int N  = in_sizes[0] / 128;  // 20000 drugs  (< 65536: ushort csr ok)
    const int E  = in_sizes[2];        // 1.5M dd edges
    const int EN = in_sizes[8];        // 1.5M neg edges
    const int CHUNK = (E + NPART - 1) / NPART;
    const int M8 = NPART * N;

    // workspace layout
    char* ws = (char*)d_ws;
    int*            deg8    = (int*)ws;            ws += (size_t)M8 * 4;
    int*            off8    = (int*)ws;            ws += (size_t)M8 * 4;
    int*            cursor8 = (int*)ws;            ws += (size_t)M8 * 4;
    unsigned short* csr16   = (unsigned short*)ws; ws += (size_t)E * 2;
    ws = (char*)(((size_t)ws + 3) & ~(size_t)3);
    unsigned short* msg1    = (unsigned short*)ws; ws += (size_t)N * 64 * 2;
    unsigned short* self1   = (unsigned short*)ws; ws += (size_t)N * 64 * 2;
    unsigned short* msg2    = (unsigned short*)ws; ws += (size_t)N * 32 * 2;
    unsigned short* self2   = (unsigned short*)ws; ws += (size_t)N * 32 * 2;
    unsigned short* h2      = (unsigned short*)ws; ws += (size_t)N * 32 * 2;
    ws = (char*)(((size_t)ws + 3) & ~(size_t)3);
    float*          h1      = (float*)ws;          ws += (size_t)N * 64 * 4;

    float* pos = (float*)d_out;
    float* neg = pos + E;

    hipMemsetAsync(deg8, 0, (size_t)M8 * sizeof(int), stream);

    // ---- CSR-by-dst build (edge-chunk partitioned, nt streaming reads) ----
    degree8_kernel<<<2048, 256, 0, stream>>>(dd_dst, deg8, E, CHUNK, N);
    scan8_kernel<<<NPART, 1024, 0, stream>>>(deg8, off8, cursor8, N, CHUNK);
    fill8_kernel<<<2048, 256, 0, stream>>>(dd_src, dd_dst, cursor8, csr16, E, CHUNK, N);

    // ---- layer 1: register-weight GEMMs -> bf16 msg/self ----
    gemm_reg_kernel<128><<<512, 256, 0, stream>>>(feat_drug, W1_dd, msg1, N);
    gemm_reg_kernel<128><<<512, 256, 0, stream>>>(feat_drug, W1_self_drug, self1, N);
    gather_combine_kernel<64, true, false><<<(N + 3) / 4, 256, 0, stream>>>(
        msg1, csr16, off8, cursor8, self1, b1, h1, N);

    // ---- layer 2: fused dual-matrix register GEMM -> bf16 ----
    gemm2_reg_kernel<<<512, 256, 0, stream>>>(h1, W2_dd, W2_self_drug, msg2, self2, N);
    gather_combine_kernel<32, false, true><<<(N + 7) / 8, 256, 0, stream>>>(
        msg2, csr16, off8, cursor8, self2, b2, h2, N);

    // ---- scorer (pos + neg fused, bf16 h2) ----
    score2_kernel<<<4096, 256, 0, stream>>>(h2, dd_src, dd_dst, neg_src, neg_dst,
                                            w_rel, pos, neg, E, EN);
}

// Round 10
// 409.857 us; speedup vs baseline: 1.0847x; 1.0847x over previous
//
#include <hip/hip_runtime.h>

// ---------------------------------------------------------------------------
// Drug-path-only GNN (gene path is dead code w.r.t. outputs).
// Round 10: (a) revert nt loads on csr/selfb in the gather -- round-9 showed
// broadcast csr lines are reused across adjacent waves, and evict-first
// forced HBM re-fetch (gather FETCH 22MB, 75us). nt stays only on truly
// single-use streams (edge lists in degree/fill/score, score output).
// (b) slot-vectorized gather: one wave per node, each lane loads a uint
// (2 bf16 feats) so one instruction fetches 2 rows (W=64) / 4 rows (W=32);
// slots combined by shfl_xor. score2: 4 lanes/edge with uint4 (16B) loads.
// ---------------------------------------------------------------------------

#define NPART 8

__device__ inline float bf2f(unsigned short b) {
    union { float f; unsigned u; } c; c.u = (unsigned)b << 16; return c.f;
}
__device__ inline unsigned short f2bf(float x) {
    union { float f; unsigned u; } c; c.f = x;
    unsigned r = c.u + 0x7FFF + ((c.u >> 16) & 1);
    return (unsigned short)(r >> 16);
}
__device__ inline float bflo(unsigned u) { return bf2f((unsigned short)(u & 0xFFFF)); }
__device__ inline float bfhi(unsigned u) { return bf2f((unsigned short)(u >> 16)); }

// out[m][n] = bf16(sum_k A[m][k]*W[k][n]); KOUT==64; weights in VGPRs
template<int KIN>
__global__ __launch_bounds__(256) void gemm_reg_kernel(const float* __restrict__ A,
                                                       const float* __restrict__ W,
                                                       unsigned short* __restrict__ out,
                                                       int M) {
    const int lane = threadIdx.x & 63;
    const int gwave = blockIdx.x * (blockDim.x >> 6) + (threadIdx.x >> 6);
    const int nwave = gridDim.x * (blockDim.x >> 6);
    float w[KIN];
#pragma unroll
    for (int k = 0; k < KIN; ++k) w[k] = W[k * 64 + lane];
    for (int m0 = gwave * 2; m0 < M; m0 += nwave * 2) {
        const int mu = __builtin_amdgcn_readfirstlane(m0);
        const float* a0 = A + (size_t)mu * KIN;
        const float* a1 = a0 + KIN;
        const bool two = (mu + 1) < M;
        float acc0 = 0.0f, acc1 = 0.0f;
#pragma unroll
        for (int k = 0; k < KIN; ++k) {
            const float av0 = a0[k];
            const float av1 = two ? a1[k] : 0.0f;
            acc0 = fmaf(av0, w[k], acc0);
            acc1 = fmaf(av1, w[k], acc1);
        }
        out[(size_t)mu * 64 + lane] = f2bf(acc0);
        if (two) out[(size_t)(mu + 1) * 64 + lane] = f2bf(acc1);
    }
}

// layer-2 pair: KIN=64, KOUT=32. Lanes 0..31 -> Wa cols, lanes 32..63 -> Wb.
__global__ __launch_bounds__(256) void gemm2_reg_kernel(const float* __restrict__ A,
                                                        const float* __restrict__ Wa,
                                                        const float* __restrict__ Wb,
                                                        unsigned short* __restrict__ out_a,
                                                        unsigned short* __restrict__ out_b,
                                                        int M) {
    const int lane = threadIdx.x & 63;
    const int col = lane & 31;
    const float* Wm = (lane < 32) ? Wa : Wb;
    unsigned short* om = (lane < 32) ? out_a : out_b;
    const int gwave = blockIdx.x * (blockDim.x >> 6) + (threadIdx.x >> 6);
    const int nwave = gridDim.x * (blockDim.x >> 6);
    float w[64];
#pragma unroll
    for (int k = 0; k < 64; ++k) w[k] = Wm[k * 32 + col];
    for (int m0 = gwave * 2; m0 < M; m0 += nwave * 2) {
        const int mu = __builtin_amdgcn_readfirstlane(m0);
        const float* a0 = A + (size_t)mu * 64;
        const float* a1 = a0 + 64;
        const bool two = (mu + 1) < M;
        float acc0 = 0.0f, acc1 = 0.0f;
#pragma unroll
        for (int k = 0; k < 64; ++k) {
            const float av0 = a0[k];
            const float av1 = two ? a1[k] : 0.0f;
            acc0 = fmaf(av0, w[k], acc0);
            acc1 = fmaf(av1, w[k], acc1);
        }
        om[(size_t)mu * 32 + col] = f2bf(acc0);
        if (two) om[(size_t)(mu + 1) * 32 + col] = f2bf(acc1);
    }
}

// per-edge-chunk degree histogram into partition-private deg8[p][n]
__global__ __launch_bounds__(256) void degree8_kernel(const int* __restrict__ dst,
                                                      int* __restrict__ deg8,
                                                      int E, int chunk, int N) {
    const int p = blockIdx.x & (NPART - 1);
    const int lo = p * chunk;
    const int hi = min(lo + chunk, E);
    int* __restrict__ deg = deg8 + (size_t)p * N;
    const int bip = blockIdx.x >> 3;
    const int stride = (gridDim.x >> 3) * 256;
    for (int e = lo + bip * 256 + threadIdx.x; e < hi; e += stride) {
        const int d = __builtin_nontemporal_load(dst + e);
        atomicAdd(&deg[d], 1);
    }
}

// 8 independent within-partition scans; block p's base offset = p*chunk.
__global__ __launch_bounds__(1024) void scan8_kernel(const int* __restrict__ deg8,
                                                     int* __restrict__ off8,
                                                     int* __restrict__ cursor8,
                                                     int N, int chunk) {
    const int p = blockIdx.x;
    const int base = p * chunk;
    const int* __restrict__ deg = deg8 + (size_t)p * N;
    int* __restrict__ off = off8 + (size_t)p * N;
    int* __restrict__ cur = cursor8 + (size_t)p * N;
    __shared__ int part[1024];
    const int t = threadIdx.x;
    const int per = (N + 1023) / 1024;
    const int beg = t * per;
    const int end = min(beg + per, N);
    int s = 0;
    for (int i = beg; i < end; ++i) s += deg[i];
    part[t] = s;
    __syncthreads();
    for (int d = 1; d < 1024; d <<= 1) {
        int v = (t >= d) ? part[t - d] : 0;
        __syncthreads();
        part[t] += v;
        __syncthreads();
    }
    int run = base + ((t == 0) ? 0 : part[t - 1]);
    for (int i = beg; i < end; ++i) { off[i] = run; cur[i] = run; run += deg[i]; }
}

// edge-chunk-partitioned bucket fill; nt edge reads, cached scatter stores.
__global__ __launch_bounds__(256) void fill8_kernel(const int* __restrict__ src,
                                                    const int* __restrict__ dst,
                                                    int* __restrict__ cursor8,
                                                    unsigned short* __restrict__ csr_src,
                                                    int E, int chunk, int N) {
    const int p = blockIdx.x & (NPART - 1);
    const int lo = p * chunk;
    const int hi = min(lo + chunk, E);
    int* __restrict__ cursor = cursor8 + (size_t)p * N;
    const int bip = blockIdx.x >> 3;
    const int stride = (gridDim.x >> 3) * 256;
    for (int e = lo + bip * 256 + threadIdx.x; e < hi; e += stride) {
        const int d = __builtin_nontemporal_load(dst + e);
        const int s = __builtin_nontemporal_load(src + e);
        const int pos = atomicAdd(&cursor[d], 1);
        csr_src[pos] = (unsigned short)s;
    }
}

// Slot-vectorized gather: one wave per node. lane = slot*(W/2) + fp;
// each lane accumulates feature pair (2fp, 2fp+1) of every SLOTS-th edge via
// uint loads; slots are summed with shfl_xor at the end.
template<int W, bool RELU, bool OBF>
__global__ __launch_bounds__(256) void gather2_kernel(
        const unsigned short* __restrict__ msg,
        const unsigned short* __restrict__ csr,
        const int* __restrict__ off8, const int* __restrict__ end8,
        const unsigned short* __restrict__ selfb, const float* __restrict__ b,
        void* __restrict__ out_, int N) {
    constexpr int PAIRS = W / 2;        // feature-pairs per row (32 or 16)
    constexpr int SLOTS = 64 / PAIRS;   // edge rows per load instruction (2 or 4)
    const int lane = threadIdx.x & 63;
    const int fp   = lane & (PAIRS - 1);
    const int slot = lane / PAIRS;
    const int wid  = (blockIdx.x * blockDim.x + threadIdx.x) >> 6;
    const int nw   = (gridDim.x * blockDim.x) >> 6;
    const float bk0 = b[2 * fp], bk1 = b[2 * fp + 1];
    for (int n = wid; n < N; n += nw) {
        float a0 = 0.0f, a1 = 0.0f;
        int cnt = 0;
        for (int p = 0; p < NPART; ++p) {
            const int beg = off8[(size_t)p * N + n];
            const int end = end8[(size_t)p * N + n];
            cnt += end - beg;
            for (int i = beg; i < end; i += SLOTS) {
                const int e = i + slot;
                const bool valid = e < end;
                const int s = valid ? (int)csr[e] : 0;
                const unsigned u = *(const unsigned*)(msg + (size_t)s * W + fp * 2);
                if (valid) { a0 += bflo(u); a1 += bfhi(u); }
            }
        }
#pragma unroll
        for (int d = PAIRS; d < 64; d <<= 1) {
            a0 += __shfl_xor(a0, d, 64);
            a1 += __shfl_xor(a1, d, 64);
        }
        if (slot == 0) {
            const float dn = (cnt > 0) ? (float)cnt : 1.0f;
            const unsigned sb = *(const unsigned*)(selfb + (size_t)n * W + fp * 2);
            float v0 = a0 / dn + bflo(sb) + bk0;
            float v1 = a1 / dn + bfhi(sb) + bk1;
            if (RELU) { v0 = fmaxf(v0, 0.0f); v1 = fmaxf(v1, 0.0f); }
            if (OBF) {
                ((unsigned*)out_)[(size_t)n * PAIRS + fp] =
                    (unsigned)f2bf(v0) | ((unsigned)f2bf(v1) << 16);
            } else {
                ((float2*)out_)[(size_t)n * PAIRS + fp] = make_float2(v0, v1);
            }
        }
    }
}

// fused pos+neg scorer over bf16 h: 4 lanes/edge, uint4 (16B = 8 feats) loads
__global__ __launch_bounds__(256) void score2_kernel(const unsigned short* __restrict__ h,
                                                     const int* __restrict__ sA,
                                                     const int* __restrict__ dA,
                                                     const int* __restrict__ sB,
                                                     const int* __restrict__ dB,
                                                     const float* __restrict__ wrel,
                                                     float* __restrict__ outA,
                                                     float* __restrict__ outB,
                                                     int EA, int EB) {
    const int lj = threadIdx.x & 3;
    const size_t grp = ((size_t)blockIdx.x * blockDim.x + threadIdx.x) >> 2;
    const size_t ngrp = ((size_t)gridDim.x * blockDim.x) >> 2;
    float w[8];
#pragma unroll
    for (int j = 0; j < 8; ++j) w[j] = wrel[lj * 8 + j];
    const size_t total = (size_t)EA + (size_t)EB;
    for (size_t e = grp; e < total; e += ngrp) {
        int s, d; float* o;
        if (e < (size_t)EA) {
            s = __builtin_nontemporal_load(sA + e);
            d = __builtin_nontemporal_load(dA + e);
            o = outA + e;
        } else {
            const size_t e2 = e - EA;
            s = __builtin_nontemporal_load(sB + e2);
            d = __builtin_nontemporal_load(dB + e2);
            o = outB + e2;
        }
        const uint4 us = *(const uint4*)(h + (size_t)s * 32 + lj * 8);
        const uint4 ud = *(const uint4*)(h + (size_t)d * 32 + lj * 8);
        float p = bflo(us.x) * w[0] * bflo(ud.x) + bfhi(us.x) * w[1] * bfhi(ud.x)
                + bflo(us.y) * w[2] * bflo(ud.y) + bfhi(us.y) * w[3] * bfhi(ud.y)
                + bflo(us.z) * w[4] * bflo(ud.z) + bfhi(us.z) * w[5] * bfhi(ud.z)
                + bflo(us.w) * w[6] * bflo(ud.w) + bfhi(us.w) * w[7] * bfhi(ud.w);
        p += __shfl_xor(p, 1, 64);
        p += __shfl_xor(p, 2, 64);
        if (lj == 0) __builtin_nontemporal_store(p, o);
    }
}

extern "C" void kernel_launch(void* const* d_in, const int* in_sizes, int n_in,
                              void* d_out, int out_size, void* d_ws, size_t ws_size,
                              hipStream_t stream) {
    const float* feat_drug    = (const float*)d_in[0];
    const int*   dd_src       = (const int*)d_in[2];
    const int*   dd_dst       = (const int*)d_in[3];
    const int*   neg_src      = (const int*)d_in[8];
    const int*   neg_dst      = (const int*)d_in[9];
    const float* W1_dd        = (const float*)d_in[10];
    const float* W1_self_drug = (const float*)d_in[13];
    const float* b1           = (const float*)d_in[15];
    const float* W2_dd        = (const float*)d_in[16];
    const float* W2_self_drug = (const float*)d_in[19];
    const float* b2           = (const float*)d_in[21];
    const float* w_rel        = (const float*)d_in[22];

    const int N  = in_sizes[0] / 128;  // 20000 drugs  (< 65536: ushort csr ok)
    const int E  = in_sizes[2];        // 1.5M dd edges
    const int EN = in_sizes[8];        // 1.5M neg edges
    const int CHUNK = (E + NPART - 1) / NPART;
    const int M8 = NPART * N;

    // workspace layout
    char* ws = (char*)d_ws;
    int*            deg8    = (int*)ws;            ws += (size_t)M8 * 4;
    int*            off8    = (int*)ws;            ws += (size_t)M8 * 4;
    int*            cursor8 = (int*)ws;            ws += (size_t)M8 * 4;
    unsigned short* csr16   = (unsigned short*)ws; ws += (size_t)E * 2;
    ws = (char*)(((size_t)ws + 15) & ~(size_t)15);
    unsigned short* msg1    = (unsigned short*)ws; ws += (size_t)N * 64 * 2;
    unsigned short* self1   = (unsigned short*)ws; ws += (size_t)N * 64 * 2;
    unsigned short* msg2    = (unsigned short*)ws; ws += (size_t)N * 32 * 2;
    unsigned short* self2   = (unsigned short*)ws; ws += (size_t)N * 32 * 2;
    unsigned short* h2      = (unsigned short*)ws; ws += (size_t)N * 32 * 2;
    ws = (char*)(((size_t)ws + 15) & ~(size_t)15);
    float*          h1      = (float*)ws;          ws += (size_t)N * 64 * 4;

    float* pos = (float*)d_out;
    float* neg = pos + E;

    hipMemsetAsync(deg8, 0, (size_t)M8 * sizeof(int), stream);

    // ---- CSR-by-dst build (edge-chunk partitioned, nt streaming reads) ----
    degree8_kernel<<<2048, 256, 0, stream>>>(dd_dst, deg8, E, CHUNK, N);
    scan8_kernel<<<NPART, 1024, 0, stream>>>(deg8, off8, cursor8, N, CHUNK);
    fill8_kernel<<<2048, 256, 0, stream>>>(dd_src, dd_dst, cursor8, csr16, E, CHUNK, N);

    // ---- layer 1: register-weight GEMMs -> bf16 msg/self ----
    gemm_reg_kernel<128><<<512, 256, 0, stream>>>(feat_drug, W1_dd, msg1, N);
    gemm_reg_kernel<128><<<512, 256, 0, stream>>>(feat_drug, W1_self_drug, self1, N);
    gather2_kernel<64, true, false><<<(N + 3) / 4, 256, 0, stream>>>(
        msg1, csr16, off8, cursor8, self1, b1, h1, N);

    // ---- layer 2: fused dual-matrix register GEMM -> bf16 ----
    gemm2_reg_kernel<<<512, 256, 0, stream>>>(h1, W2_dd, W2_self_drug, msg2, self2, N);
    gather2_kernel<32, false, true><<<(N + 3) / 4, 256, 0, stream>>>(
        msg2, csr16, off8, cursor8, self2, b2, h2, N);

    // ---- scorer (pos + neg fused, bf16 h2, 4 lanes/edge) ----
    score2_kernel<<<4096, 256, 0, stream>>>(h2, dd_src, dd_dst, neg_src, neg_dst,
                                            w_rel, pos, neg, E, EN);
}